// Round 1
// 186.318 us; speedup vs baseline: 1.0280x; 1.0280x over previous
//
#include <hip/hip_runtime.h>
#include <hip/hip_bf16.h>

// Problem: B=2, S=2048, C=U=1024, H=16, dh=64. I/O FP32.
// 4 dispatches: prep (cast X->bf16 + transpose/cast W->bf16 + zero stats),
// QKV GEMM (m97-style staging; Q pre-scaled; V written directly in [b,h,d,s]),
// flash attention (LPT+XCD grid, async global_load_lds staging into
// XOR-swizzled LDS, offset-free exp2 softmax, fused residual+LN-stats),
// LN apply.

typedef __bf16 bf16_t;
typedef __bf16 bf16x8 __attribute__((ext_vector_type(8)));
typedef __bf16 bf16x4 __attribute__((ext_vector_type(4)));
typedef _Float16 f16_t;
typedef _Float16 f16x2 __attribute__((ext_vector_type(2)));
typedef _Float16 f16x4 __attribute__((ext_vector_type(4)));
typedef _Float16 f16x8 __attribute__((ext_vector_type(8)));
typedef float f32x4 __attribute__((ext_vector_type(4)));

constexpr int Bsz = 2;
constexpr int Seq = 2048;
constexpr int Cdim = 1024;   // == U
constexpr int Udim = 1024;
constexpr int Hn = 16;
constexpr int Dh = 64;
constexpr int Mrows = Bsz * Seq;          // 4096
constexpr int PerBatch = Seq * Udim;      // 2^21
constexpr float SCLQ = 0.125f * 1.44269504088896340736f;  // /sqrt(dh) * log2e

#if __has_builtin(__builtin_amdgcn_exp2f)
#define EXP2F(x) __builtin_amdgcn_exp2f(x)
#else
#define EXP2F(x) exp2f(x)
#endif

// async global->LDS, 16B per lane; LDS dest = wave-uniform base + lane*16
__device__ __forceinline__ void gload16(const void* g, void* l)
{
    __builtin_amdgcn_global_load_lds(
        (const __attribute__((address_space(1))) void*)g,
        (__attribute__((address_space(3))) void*)l, 16, 0, 0);
}

// pack two f32 -> f16x2 via v_cvt_pkrtz (returns __fp16x2; bit-identical)
__device__ __forceinline__ f16x2 pkrtz(float a, float b)
{
    return __builtin_bit_cast(f16x2, __builtin_amdgcn_cvt_pkrtz(a, b));
}

// ---------------------------------------------------------------- prep
__global__ __launch_bounds__(256)
void prep(const float* __restrict__ X,
          const float* __restrict__ Wq, const float* __restrict__ Wk,
          const float* __restrict__ Wv,
          bf16_t* __restrict__ Xb,
          bf16_t* __restrict__ Tq, bf16_t* __restrict__ Tk,
          bf16_t* __restrict__ Tv, float* __restrict__ stats)
{
    int z = blockIdx.z;
    int tid = threadIdx.x;
    if (z < 3) {
        const float* W = (z == 0) ? Wq : (z == 1) ? Wk : Wv;
        bf16_t* T = (z == 0) ? Tq : (z == 1) ? Tk : Tv;
        __shared__ bf16_t t[64][65];
        int x0 = blockIdx.x * 64, y0 = blockIdx.y * 64;
        int tx = tid & 63, ty = tid >> 6;
        for (int i = ty; i < 64; i += 4)
            t[i][tx] = (bf16_t)W[(size_t)(y0 + i) * Cdim + x0 + tx];
        __syncthreads();
        for (int i = ty; i < 64; i += 4)
            T[(size_t)(x0 + i) * Cdim + y0 + tx] = t[tx][i];
    } else {
        int bi = blockIdx.y * 16 + blockIdx.x;          // 0..255
        if (bi == 0 && tid < 4) stats[tid] = 0.0f;
        const float4* Xv = (const float4*)X;
#pragma unroll
        for (int k = 0; k < 16; k++) {
            int i = bi * 4096 + k * 256 + tid;          // 1M float4 total
            float4 v = Xv[i];
            bf16x4 o = { (bf16_t)v.x, (bf16_t)v.y, (bf16_t)v.z, (bf16_t)v.w };
            *(bf16x4*)(Xb + (size_t)i * 4) = o;
        }
    }
}

// ---------------------------------------------------------------- QKV GEMM
// m97 structure: 128x128 tile, BK=32, unpadded LDS, global_load_lds width 16.
// z==0: Q pre-scaled by SCLQ. z==1: K. z==2: V -> Vt[b][h][d][s].
__global__ __launch_bounds__(256)
void gemm_qkv(const bf16_t* __restrict__ X,
              const bf16_t* __restrict__ Wt0, const bf16_t* __restrict__ Wt1,
              const bf16_t* __restrict__ Wt2,
              const float* __restrict__ b0, const float* __restrict__ b1,
              const float* __restrict__ b2,
              f16_t* __restrict__ O0, f16_t* __restrict__ O1, f16_t* __restrict__ O2v)
{
    int z = blockIdx.z;
    const bf16_t* Wt = (z == 0) ? Wt0 : (z == 1) ? Wt1 : Wt2;
    const float* bias = (z == 0) ? b0 : (z == 1) ? b1 : b2;
    float scl = (z == 0) ? SCLQ : 1.0f;

    constexpr int Kd = 1024, Nd = 1024;
    __shared__ __align__(16) bf16_t As[128 * 32];
    __shared__ __align__(16) bf16_t Bs[128 * 32];

    int tid = threadIdx.x;
    int wave = tid >> 6, lane = tid & 63, quad = lane >> 4, l16 = lane & 15;
    int wm = (wave & 1) * 64, wn = (wave >> 1) * 64;
    int m0 = blockIdx.y * 128, n0 = blockIdx.x * 128;

    f32x4 acc[4][4] = {};

    int e0 = wave * 512 + lane * 8;
    int r0 = e0 >> 5, c0 = e0 & 31;
    int e1 = e0 + 2048;
    int r1 = e1 >> 5, c1 = e1 & 31;
    const bf16_t* Ag = X + (size_t)m0 * Kd;
    const bf16_t* Bg = Wt + (size_t)n0 * Kd;
    bf16_t* AsW0 = As + wave * 512;
    bf16_t* AsW1 = As + 2048 + wave * 512;
    bf16_t* BsW0 = Bs + wave * 512;
    bf16_t* BsW1 = Bs + 2048 + wave * 512;

    for (int k0 = 0; k0 < Kd; k0 += 32) {
        gload16(Ag + (size_t)r0 * Kd + k0 + c0, AsW0);
        gload16(Ag + (size_t)r1 * Kd + k0 + c1, AsW1);
        gload16(Bg + (size_t)r0 * Kd + k0 + c0, BsW0);
        gload16(Bg + (size_t)r1 * Kd + k0 + c1, BsW1);
        __syncthreads();

        bf16x8 af[4], bfr[4];
#pragma unroll
        for (int i = 0; i < 4; i++)
            af[i] = *(const bf16x8*)&As[(wm + i * 16 + l16) * 32 + quad * 8];
#pragma unroll
        for (int i = 0; i < 4; i++)
            bfr[i] = *(const bf16x8*)&Bs[(wn + i * 16 + l16) * 32 + quad * 8];
#pragma unroll
        for (int mt = 0; mt < 4; mt++)
#pragma unroll
            for (int nt = 0; nt < 4; nt++)
                acc[mt][nt] = __builtin_amdgcn_mfma_f32_16x16x32_bf16(
                    af[mt], bfr[nt], acc[mt][nt], 0, 0, 0);
        __syncthreads();
    }

    if (z < 2) {
        f16_t* Og = (z == 0) ? O0 : O1;
#pragma unroll
        for (int nt = 0; nt < 4; nt++) {
            int col = n0 + wn + nt * 16 + l16;
            float bv = bias[col];
#pragma unroll
            for (int mt = 0; mt < 4; mt++) {
                int row = m0 + wm + mt * 16 + quad * 4;
#pragma unroll
                for (int r = 0; r < 4; r++)
                    Og[(size_t)(row + r) * Nd + col] = (f16_t)((acc[mt][nt][r] + bv) * scl);
            }
        }
    } else {
        int bb = m0 >> 11;
#pragma unroll
        for (int nt = 0; nt < 4; nt++) {
            int col = n0 + wn + nt * 16 + l16;
            float bv = bias[col];
            int h = col >> 6, d = col & 63;
            f16_t* vbase = O2v + (((size_t)(bb * Hn + h) * Dh + d) << 11);
#pragma unroll
            for (int mt = 0; mt < 4; mt++) {
                int row = m0 + wm + mt * 16 + quad * 4;
                int s = row & (Seq - 1);
                f16x4 pk;
#pragma unroll
                for (int r = 0; r < 4; r++) pk[r] = (f16_t)(acc[mt][nt][r] + bv);
                *(f16x4*)(vbase + s) = pk;
            }
        }
    }
}

// ---------------------------------------------------------------- attention
// 1024 blocks, one 64-row qtile each. LPT + XCD swizzle.
// Staging: global_load_lds width-16 into unpadded [64][64] f16 tiles with
// XOR swizzle (chunk ^= row&7) applied on the PRE-SWIZZLED global source
// (rule #21: gload_lds writes linearly; source perm == read perm).
// Swizzled read addresses are lane-constant bases + compile-time offsets
// (kv-loop unrolled by 2 so buf is a literal). One barrier per tile; the
// barrier's implicit vmcnt(0) drains next-tile loads issued at tile start.
// Offset-free exp2 softmax; peeled diagonal; fused residual + LN stats.
__global__ __launch_bounds__(256)
void attn8(const f16_t* __restrict__ Q, const f16_t* __restrict__ K,
           const f16_t* __restrict__ Vt, const float* __restrict__ X,
           bf16_t* __restrict__ R, float* __restrict__ stats)
{
    int id = blockIdx.x;
    int c = id & 7;            // XCD slot (4 bh per XCD -> K/V L2-resident)
    int r8 = id >> 3;
    int g = r8 & 3;
    int kk = r8 >> 2;
    int bh = (g << 3) | c;
    int b = bh >> 4, h = bh & 15;
    int qtile = 31 - kk;       // heavy first (LPT)

    int tid = threadIdx.x;
    int w = tid >> 6, lane = tid & 63, quad = lane >> 4, l16 = lane & 15;
    size_t bS = (size_t)b * Seq;

    // unpadded swizzled tiles: [buf][64 rows][64 f16 = 128B]
    __shared__ __align__(16) f16_t Ks[2][4096];   // rows = kv, cols = d
    __shared__ __align__(16) f16_t Vs[2][4096];   // rows = d,  cols = kv

    const f16_t* Kg = K + bS * Udim + h * Dh;
    const f16_t* Vg = Vt + ((size_t)(b * Hn + h)) * Dh * Seq;

    // staging geometry: lds dest byte = round*4096 + w*1024 + lane*16
    //   row = round*32 + w*8 + (lane>>3), phys chunk = lane&7
    //   logical chunk = (lane&7) ^ (row&7); row&7 == (lane>>3)&7
    int srow = w * 8 + (lane >> 3);
    int schunk = (lane & 7) ^ ((lane >> 3) & 7);
    const f16_t* kp0 = Kg + (size_t)srow * Udim + schunk * 8;
    const f16_t* kp1 = kp0 + (size_t)32 * Udim;
    const f16_t* vp0 = Vg + (size_t)srow * Seq + schunk * 8;
    const f16_t* vp1 = vp0 + (size_t)32 * Seq;

    int q0 = qtile * 64 + w * 16;
    int qidx = q0 + l16;
    const f16_t* Qp = Q + (bS + qidx) * Udim + h * Dh;
    f16x8 qf[2];
#pragma unroll
    for (int s = 0; s < 2; s++) qf[s] = *(const f16x8*)(Qp + s * 32 + quad * 8);

    // lane-constant swizzled read offsets (f16 elements)
    // QK frag:  K[kv=t*16+l16][d = s*32+quad*8..+7]
    //   phys = (t*16+l16)*64 + 8*((4s+quad)^(l16&7))           (+ t*1024)
    // PV frag:  V[d=dt*16+l16][kv = t*16+quad*4..+3]
    //   phys byte = d*128 + ((t*32+quad*8) ^ ((l16&7)<<4))     (+ dt*2048)
    int m = l16 & 7;
    int kO0 = l16 * 64 + ((quad ^ m) << 3);
    int kO1 = l16 * 64 + (((4 + quad) ^ m) << 3);
    int vO[4];
#pragma unroll
    for (int t = 0; t < 4; t++)
        vO[t] = l16 * 64 + (((t * 32 + quad * 8) ^ (m << 4)) >> 1);

    f32x4 Oacc[4] = {};
    float lsum = 0.0f;

    // preload tile 0 into buf 0
    gload16(kp0, &Ks[0][w * 512]);
    gload16(kp1, &Ks[0][2048 + w * 512]);
    gload16(vp0, &Vs[0][w * 512]);
    gload16(vp1, &Vs[0][2048 + w * 512]);
    kp0 += (size_t)64 * Udim; kp1 += (size_t)64 * Udim;
    vp0 += 64; vp1 += 64;
    __syncthreads();

#define TILE(BUF)                                                              \
    do {                                                                       \
        /* stage next tile into BUF^1 (async; drained by end barrier) */       \
        gload16(kp0, &Ks[(BUF) ^ 1][w * 512]);                                 \
        gload16(kp1, &Ks[(BUF) ^ 1][2048 + w * 512]);                          \
        gload16(vp0, &Vs[(BUF) ^ 1][w * 512]);                                 \
        gload16(vp1, &Vs[(BUF) ^ 1][2048 + w * 512]);                          \
        kp0 += (size_t)64 * Udim; kp1 += (size_t)64 * Udim;                    \
        vp0 += 64; vp1 += 64;                                                  \
        f32x4 st[4];                                                           \
        _Pragma("unroll")                                                      \
        for (int t = 0; t < 4; t++) {                                          \
            f32x4 a = {};                                                      \
            f16x8 kf0 = *(const f16x8*)&Ks[BUF][kO0 + t * 1024];               \
            a = __builtin_amdgcn_mfma_f32_16x16x32_f16(kf0, qf[0], a, 0, 0, 0);\
            f16x8 kf1 = *(const f16x8*)&Ks[BUF][kO1 + t * 1024];               \
            a = __builtin_amdgcn_mfma_f32_16x16x32_f16(kf1, qf[1], a, 0, 0, 0);\
            st[t] = a;                                                         \
        }                                                                      \
        f16x4 pf[4];                                                           \
        _Pragma("unroll")                                                      \
        for (int t = 0; t < 4; t++) {                                          \
            float p0 = EXP2F(st[t][0]);                                        \
            float p1 = EXP2F(st[t][1]);                                        \
            float p2 = EXP2F(st[t][2]);                                        \
            float p3 = EXP2F(st[t][3]);                                        \
            lsum += (p0 + p1) + (p2 + p3);                                     \
            f16x2 lo = pkrtz(p0, p1);                                          \
            f16x2 hi = pkrtz(p2, p3);                                          \
            pf[t][0] = lo[0]; pf[t][1] = lo[1];                                \
            pf[t][2] = hi[0]; pf[t][3] = hi[1];                                \
        }                                                                      \
        _Pragma("unroll")                                                      \
        for (int t = 0; t < 4; t++) {                                          \
            _Pragma("unroll")                                                  \
            for (int dt = 0; dt < 4; dt++) {                                   \
                f16x4 vf = *(const f16x4*)&Vs[BUF][vO[t] + dt * 1024];         \
                Oacc[dt] = __builtin_amdgcn_mfma_f32_16x16x16f16(              \
                    vf, pf[t], Oacc[dt], 0, 0, 0);                             \
            }                                                                  \
        }                                                                      \
        __syncthreads();                                                       \
    } while (0)

    // ---- main loop: all kv strictly below the diagonal tile, mask-free.
    // unrolled by 2 so buf is a compile-time literal (LDS offset immediates)
    {
        int i = 0;
        for (; i + 2 <= qtile; i += 2) { TILE(0); TILE(1); }
        if (i < qtile) { TILE(0); }
    }
#undef TILE

    // ---- peeled diagonal tile, causal-masked, t<=w only (wave-uniform)
    {
        int dbuf = qtile & 1;
        int kv0 = qtile * 64;
#pragma unroll
        for (int t = 0; t < 4; t++) {
            if (t <= w) {
                f32x4 a = {};
                f16x8 kf0 = *(const f16x8*)&Ks[dbuf][kO0 + t * 1024];
                a = __builtin_amdgcn_mfma_f32_16x16x32_f16(kf0, qf[0], a, 0, 0, 0);
                f16x8 kf1 = *(const f16x8*)&Ks[dbuf][kO1 + t * 1024];
                a = __builtin_amdgcn_mfma_f32_16x16x32_f16(kf1, qf[1], a, 0, 0, 0);
                f16x4 pfd;
#pragma unroll
                for (int r = 0; r < 4; r++) {
                    float sv = a[r];
                    if (kv0 + t * 16 + quad * 4 + r > qidx) sv = -1e30f;  // causal
                    float pv = EXP2F(sv);
                    lsum += pv;
                    pfd[r] = (f16_t)pv;
                }
#pragma unroll
                for (int dt = 0; dt < 4; dt++) {
                    f16x4 vf = *(const f16x4*)&Vs[dbuf][vO[t] + dt * 1024];
                    Oacc[dt] = __builtin_amdgcn_mfma_f32_16x16x16f16(
                        vf, pfd, Oacc[dt], 0, 0, 0);
                }
            }
        }
    }

    lsum += __shfl_xor(lsum, 16);
    lsum += __shfl_xor(lsum, 32);
    float invl = 1.0f / lsum;

    float s_acc = 0.0f, ss_acc = 0.0f;
    const float* Xp = X + (bS + qidx) * Udim + h * Dh;
    bf16_t* Rp = R + (bS + qidx) * Udim + h * Dh;
#pragma unroll
    for (int dt = 0; dt < 4; dt++) {
        f32x4 xv = *(const f32x4*)(Xp + dt * 16 + quad * 4);
        f32x4 o = Oacc[dt] * invl + xv;
        bf16x4 ob;
#pragma unroll
        for (int r = 0; r < 4; r++) {
            ob[r] = (bf16_t)o[r];
            s_acc += o[r];
            ss_acc += o[r] * o[r];
        }
        *(bf16x4*)(Rp + dt * 16 + quad * 4) = ob;
    }

#pragma unroll
    for (int o = 1; o < 64; o <<= 1) {
        s_acc += __shfl_xor(s_acc, o);
        ss_acc += __shfl_xor(ss_acc, o);
    }
    __shared__ float red[8];
    if (lane == 0) { red[w] = s_acc; red[4 + w] = ss_acc; }
    __syncthreads();
    if (tid == 0) {
        atomicAdd(&stats[b], red[0] + red[1] + red[2] + red[3]);
        atomicAdd(&stats[2 + b], red[4] + red[5] + red[6] + red[7]);
    }
}

// ---------------------------------------------------------------- LN apply
__global__ __launch_bounds__(256)
void ln_norm(const bf16_t* __restrict__ R, const float* __restrict__ gamma,
             const float* __restrict__ beta, const float* __restrict__ stats,
             float* __restrict__ out)
{
    constexpr float invN = 1.0f / (float)PerBatch;
    float mu[2], inv[2];
#pragma unroll
    for (int b = 0; b < 2; b++) {
        float m = stats[b] * invN;
        float var = stats[2 + b] * invN - m * m;
        mu[b] = m;
        inv[b] = rsqrtf(var + 1e-5f);
    }
    int i = blockIdx.x * 256 + threadIdx.x;      // over 8-elem groups, 512K
    int f = i * 8;
    int b = f >> 21;
    int su = f & (PerBatch - 1);
    bf16x8 rv = *(const bf16x8*)(R + f);
    float4 g0 = *(const float4*)(gamma + su);
    float4 g1 = *(const float4*)(gamma + su + 4);
    float4 be0 = *(const float4*)(beta + su);
    float4 be1 = *(const float4*)(beta + su + 4);
    float4 o0, o1;
    o0.x = ((float)rv[0] - mu[b]) * inv[b] * g0.x + be0.x;
    o0.y = ((float)rv[1] - mu[b]) * inv[b] * g0.y + be0.y;
    o0.z = ((float)rv[2] - mu[b]) * inv[b] * g0.z + be0.z;
    o0.w = ((float)rv[3] - mu[b]) * inv[b] * g0.w + be0.w;
    o1.x = ((float)rv[4] - mu[b]) * inv[b] * g1.x + be1.x;
    o1.y = ((float)rv[5] - mu[b]) * inv[b] * g1.y + be1.y;
    o1.z = ((float)rv[6] - mu[b]) * inv[b] * g1.z + be1.z;
    o1.w = ((float)rv[7] - mu[b]) * inv[b] * g1.w + be1.w;
    *(float4*)(out + f) = o0;
    *(float4*)(out + f + 4) = o1;
}

// ---------------------------------------------------------------- launch
extern "C" void kernel_launch(void* const* d_in, const int* in_sizes, int n_in,
                              void* d_out, int out_size, void* d_ws, size_t ws_size,
                              hipStream_t stream)
{
    const float* X     = (const float*)d_in[0];
    const float* Wq    = (const float*)d_in[1];
    const float* bq    = (const float*)d_in[2];
    const float* Wk    = (const float*)d_in[3];
    const float* bk    = (const float*)d_in[4];
    const float* Wv    = (const float*)d_in[5];
    const float* bv    = (const float*)d_in[6];
    const float* gamma = (const float*)d_in[7];
    const float* beta  = (const float*)d_in[8];
    float* out = (float*)d_out;

    char* ws = (char*)d_ws;
    size_t off = 0;
    auto alloc = [&](size_t bytes) -> void* {
        void* p = ws + off;
        off += (bytes + 255) & ~(size_t)255;
        return p;
    };
    bf16_t* Xb = (bf16_t*)alloc((size_t)Mrows * Cdim * 2);
    bf16_t* Tq = (bf16_t*)alloc((size_t)Cdim * Udim * 2);
    bf16_t* Tk = (bf16_t*)alloc((size_t)Cdim * Udim * 2);
    bf16_t* Tv = (bf16_t*)alloc((size_t)Cdim * Udim * 2);
    f16_t*  Qb = (f16_t*)alloc((size_t)Mrows * Udim * 2);
    f16_t*  Kb = (f16_t*)alloc((size_t)Mrows * Udim * 2);
    f16_t*  Vtb = (f16_t*)alloc((size_t)Mrows * Udim * 2);
    bf16_t* Rb = (bf16_t*)alloc((size_t)Mrows * Udim * 2);
    float*  stats = (float*)alloc(4 * sizeof(float));

    prep<<<dim3(16, 16, 4), 256, 0, stream>>>(X, Wq, Wk, Wv, Xb, Tq, Tk, Tv, stats);
    gemm_qkv<<<dim3(8, 32, 3), 256, 0, stream>>>(Xb, Tq, Tk, Tv, bq, bk, bv, Qb, Kb, Vtb);
    attn8<<<dim3(1024), 256, 0, stream>>>(Qb, Kb, Vtb, X, Rb, stats);
    ln_norm<<<dim3(2048), 256, 0, stream>>>(Rb, gamma, beta, stats, out);
}

// Round 2
// 186.257 us; speedup vs baseline: 1.0284x; 1.0003x over previous
//
#include <hip/hip_runtime.h>
#include <hip/hip_bf16.h>

// Problem: B=2, S=2048, C=U=1024, H=16, dh=64. I/O FP32.
// 4 dispatches: prep (cast X->bf16 + transpose/cast W->bf16 + zero stats),
// QKV GEMM (m97-style staging; Q pre-scaled; V written directly in [b,h,d,s]),
// flash attention (paired-qtile uniform-work blocks, async global_load_lds
// staging into XOR-swizzled LDS, offset-free exp2 softmax, fused
// residual+LN-stats), LN apply.

typedef __bf16 bf16_t;
typedef __bf16 bf16x8 __attribute__((ext_vector_type(8)));
typedef __bf16 bf16x4 __attribute__((ext_vector_type(4)));
typedef _Float16 f16_t;
typedef _Float16 f16x2 __attribute__((ext_vector_type(2)));
typedef _Float16 f16x4 __attribute__((ext_vector_type(4)));
typedef _Float16 f16x8 __attribute__((ext_vector_type(8)));
typedef float f32x4 __attribute__((ext_vector_type(4)));

constexpr int Bsz = 2;
constexpr int Seq = 2048;
constexpr int Cdim = 1024;   // == U
constexpr int Udim = 1024;
constexpr int Hn = 16;
constexpr int Dh = 64;
constexpr int Mrows = Bsz * Seq;          // 4096
constexpr int PerBatch = Seq * Udim;      // 2^21
constexpr float SCLQ = 0.125f * 1.44269504088896340736f;  // /sqrt(dh) * log2e

#if __has_builtin(__builtin_amdgcn_exp2f)
#define EXP2F(x) __builtin_amdgcn_exp2f(x)
#else
#define EXP2F(x) exp2f(x)
#endif

#define AINL __attribute__((always_inline))

// async global->LDS, 16B per lane; LDS dest = wave-uniform base + lane*16
__device__ __forceinline__ void gload16(const void* g, void* l)
{
    __builtin_amdgcn_global_load_lds(
        (const __attribute__((address_space(1))) void*)g,
        (__attribute__((address_space(3))) void*)l, 16, 0, 0);
}

// pack two f32 -> f16x2 via v_cvt_pkrtz (returns __fp16x2; bit-identical)
__device__ __forceinline__ f16x2 pkrtz(float a, float b)
{
    return __builtin_bit_cast(f16x2, __builtin_amdgcn_cvt_pkrtz(a, b));
}

// ---------------------------------------------------------------- prep
__global__ __launch_bounds__(256)
void prep(const float* __restrict__ X,
          const float* __restrict__ Wq, const float* __restrict__ Wk,
          const float* __restrict__ Wv,
          bf16_t* __restrict__ Xb,
          bf16_t* __restrict__ Tq, bf16_t* __restrict__ Tk,
          bf16_t* __restrict__ Tv, float* __restrict__ stats)
{
    int z = blockIdx.z;
    int tid = threadIdx.x;
    if (z < 3) {
        const float* W = (z == 0) ? Wq : (z == 1) ? Wk : Wv;
        bf16_t* T = (z == 0) ? Tq : (z == 1) ? Tk : Tv;
        __shared__ bf16_t t[64][65];
        int x0 = blockIdx.x * 64, y0 = blockIdx.y * 64;
        int tx = tid & 63, ty = tid >> 6;
        for (int i = ty; i < 64; i += 4)
            t[i][tx] = (bf16_t)W[(size_t)(y0 + i) * Cdim + x0 + tx];
        __syncthreads();
        for (int i = ty; i < 64; i += 4)
            T[(size_t)(x0 + i) * Cdim + y0 + tx] = t[tx][i];
    } else {
        int bi = blockIdx.y * 16 + blockIdx.x;          // 0..255
        if (bi == 0 && tid < 4) stats[tid] = 0.0f;
        const float4* Xv = (const float4*)X;
#pragma unroll
        for (int k = 0; k < 16; k++) {
            int i = bi * 4096 + k * 256 + tid;          // 1M float4 total
            float4 v = Xv[i];
            bf16x4 o = { (bf16_t)v.x, (bf16_t)v.y, (bf16_t)v.z, (bf16_t)v.w };
            *(bf16x4*)(Xb + (size_t)i * 4) = o;
        }
    }
}

// ---------------------------------------------------------------- QKV GEMM
// m97 structure: 128x128 tile, BK=32, unpadded LDS, global_load_lds width 16.
// z==0: Q pre-scaled by SCLQ. z==1: K. z==2: V -> Vt[b][h][d][s].
__global__ __launch_bounds__(256)
void gemm_qkv(const bf16_t* __restrict__ X,
              const bf16_t* __restrict__ Wt0, const bf16_t* __restrict__ Wt1,
              const bf16_t* __restrict__ Wt2,
              const float* __restrict__ b0, const float* __restrict__ b1,
              const float* __restrict__ b2,
              f16_t* __restrict__ O0, f16_t* __restrict__ O1, f16_t* __restrict__ O2v)
{
    int z = blockIdx.z;
    const bf16_t* Wt = (z == 0) ? Wt0 : (z == 1) ? Wt1 : Wt2;
    const float* bias = (z == 0) ? b0 : (z == 1) ? b1 : b2;
    float scl = (z == 0) ? SCLQ : 1.0f;

    constexpr int Kd = 1024, Nd = 1024;
    __shared__ __align__(16) bf16_t As[128 * 32];
    __shared__ __align__(16) bf16_t Bs[128 * 32];

    int tid = threadIdx.x;
    int wave = tid >> 6, lane = tid & 63, quad = lane >> 4, l16 = lane & 15;
    int wm = (wave & 1) * 64, wn = (wave >> 1) * 64;
    int m0 = blockIdx.y * 128, n0 = blockIdx.x * 128;

    f32x4 acc[4][4] = {};

    int e0 = wave * 512 + lane * 8;
    int r0 = e0 >> 5, c0 = e0 & 31;
    int e1 = e0 + 2048;
    int r1 = e1 >> 5, c1 = e1 & 31;
    const bf16_t* Ag = X + (size_t)m0 * Kd;
    const bf16_t* Bg = Wt + (size_t)n0 * Kd;
    bf16_t* AsW0 = As + wave * 512;
    bf16_t* AsW1 = As + 2048 + wave * 512;
    bf16_t* BsW0 = Bs + wave * 512;
    bf16_t* BsW1 = Bs + 2048 + wave * 512;

    for (int k0 = 0; k0 < Kd; k0 += 32) {
        gload16(Ag + (size_t)r0 * Kd + k0 + c0, AsW0);
        gload16(Ag + (size_t)r1 * Kd + k0 + c1, AsW1);
        gload16(Bg + (size_t)r0 * Kd + k0 + c0, BsW0);
        gload16(Bg + (size_t)r1 * Kd + k0 + c1, BsW1);
        __syncthreads();

        bf16x8 af[4], bfr[4];
#pragma unroll
        for (int i = 0; i < 4; i++)
            af[i] = *(const bf16x8*)&As[(wm + i * 16 + l16) * 32 + quad * 8];
#pragma unroll
        for (int i = 0; i < 4; i++)
            bfr[i] = *(const bf16x8*)&Bs[(wn + i * 16 + l16) * 32 + quad * 8];
#pragma unroll
        for (int mt = 0; mt < 4; mt++)
#pragma unroll
            for (int nt = 0; nt < 4; nt++)
                acc[mt][nt] = __builtin_amdgcn_mfma_f32_16x16x32_bf16(
                    af[mt], bfr[nt], acc[mt][nt], 0, 0, 0);
        __syncthreads();
    }

    if (z < 2) {
        f16_t* Og = (z == 0) ? O0 : O1;
#pragma unroll
        for (int nt = 0; nt < 4; nt++) {
            int col = n0 + wn + nt * 16 + l16;
            float bv = bias[col];
#pragma unroll
            for (int mt = 0; mt < 4; mt++) {
                int row = m0 + wm + mt * 16 + quad * 4;
#pragma unroll
                for (int r = 0; r < 4; r++)
                    Og[(size_t)(row + r) * Nd + col] = (f16_t)((acc[mt][nt][r] + bv) * scl);
            }
        }
    } else {
        int bb = m0 >> 11;
#pragma unroll
        for (int nt = 0; nt < 4; nt++) {
            int col = n0 + wn + nt * 16 + l16;
            float bv = bias[col];
            int h = col >> 6, d = col & 63;
            f16_t* vbase = O2v + (((size_t)(bb * Hn + h) * Dh + d) << 11);
#pragma unroll
            for (int mt = 0; mt < 4; mt++) {
                int row = m0 + wm + mt * 16 + quad * 4;
                int s = row & (Seq - 1);
                f16x4 pk;
#pragma unroll
                for (int r = 0; r < 4; r++) pk[r] = (f16_t)(acc[mt][nt][r] + bv);
                *(f16x4*)(vbase + s) = pk;
            }
        }
    }
}

// ---------------------------------------------------------------- attention
// 512 blocks: each block owns a PAIR of qtiles (qa=31-i, qb=i) of the same
// (b,h) -> per-block work is uniform (qa+qb+2 = 33 tile-units): no drain
// tail, no load-imbalance. Staged K/V tiles are shared: for t<qb one
// ds_read fragment feeds BOTH qtiles' MFMAs. XOR-swizzled LDS fed by
// global_load_lds with pre-swizzled source (rule #21). Buffer parity kept
// compile-time via phase drivers (all `buf` args literal). Offset-free
// exp2 softmax; peeled diagonals; fused residual + LN stats.
__global__ __launch_bounds__(256)
void attn9(const f16_t* __restrict__ Q, const f16_t* __restrict__ K,
           const f16_t* __restrict__ Vt, const float* __restrict__ X,
           bf16_t* __restrict__ R, float* __restrict__ stats)
{
    int id = blockIdx.x;
    int c = id & 7;            // XCD slot (4 bh per XCD -> K/V L2-resident)
    int r = id >> 3;           // 0..63
    int g = r & 3;
    int pi = r >> 2;           // 0..15 pair index
    int bh = (g << 3) | c;
    int b = bh >> 4, h = bh & 15;
    int qa = 31 - pi;          // heavy qtile (16..31)
    int qb = pi;               // light qtile (0..15), qb < qa always

    int tid = threadIdx.x;
    int w = tid >> 6, lane = tid & 63, quad = lane >> 4, l16 = lane & 15;
    size_t bS = (size_t)b * Seq;

    // unpadded swizzled tiles: [buf][64 rows][64 f16 = 128B]
    __shared__ __align__(16) f16_t Ks[2][4096];   // rows = kv, cols = d
    __shared__ __align__(16) f16_t Vs[2][4096];   // rows = d,  cols = kv

    const f16_t* Kg = K + bS * Udim + h * Dh;
    const f16_t* Vg = Vt + ((size_t)(b * Hn + h)) * Dh * Seq;

    // staging geometry: lds dest byte = round*4096 + w*1024 + lane*16
    //   row = round*32 + w*8 + (lane>>3), phys chunk = lane&7
    //   logical chunk = (lane&7) ^ (row&7); row&7 == (lane>>3)&7
    int srow = w * 8 + (lane >> 3);
    int schunk = (lane & 7) ^ ((lane >> 3) & 7);
    const f16_t* kp0 = Kg + (size_t)srow * Udim + schunk * 8;
    const f16_t* kp1 = kp0 + (size_t)32 * Udim;
    const f16_t* vp0 = Vg + (size_t)srow * Seq + schunk * 8;
    const f16_t* vp1 = vp0 + (size_t)32 * Seq;

    int qidxA = qa * 64 + w * 16 + l16;
    int qidxB = qb * 64 + w * 16 + l16;
    const f16_t* QpA = Q + (bS + qidxA) * Udim + h * Dh;
    const f16_t* QpB = Q + (bS + qidxB) * Udim + h * Dh;
    f16x8 qfA[2], qfB[2];
#pragma unroll
    for (int s = 0; s < 2; s++) {
        qfA[s] = *(const f16x8*)(QpA + s * 32 + quad * 8);
        qfB[s] = *(const f16x8*)(QpB + s * 32 + quad * 8);
    }

    // lane-constant swizzled read offsets (f16 elements)
    // QK frag:  K[kv=t*16+l16][d = s*32+quad*8..+7]
    //   phys = (t*16+l16)*64 + 8*((4s+quad)^(l16&7))           (+ t*1024)
    // PV frag:  V[d=dt*16+l16][kv = t*16+quad*4..+3]
    //   phys byte = d*128 + ((t*32+quad*8) ^ ((l16&7)<<4))     (+ dt*2048)
    int m = l16 & 7;
    int kO0 = l16 * 64 + ((quad ^ m) << 3);
    int kO1 = l16 * 64 + (((4 + quad) ^ m) << 3);
    int vO[4];
#pragma unroll
    for (int t = 0; t < 4; t++)
        vO[t] = l16 * 64 + (((t * 32 + quad * 8) ^ (m << 4)) >> 1);

    f32x4 OA[4] = {}, OB[4] = {};
    float lsA = 0.0f, lsB = 0.0f;

    // stage one tile into buf nb (and advance pointers)
    auto STAGE = [&](int nb) AINL {
        gload16(kp0, &Ks[nb][w * 512]);
        gload16(kp1, &Ks[nb][2048 + w * 512]);
        gload16(vp0, &Vs[nb][w * 512]);
        gload16(vp1, &Vs[nb][2048 + w * 512]);
        kp0 += (size_t)64 * Udim; kp1 += (size_t)64 * Udim;
        vp0 += 64; vp1 += 64;
    };

    // full tile for A (and optionally B sharing the same K/V fragments)
    auto TILE = [&](int buf, bool withB) AINL {
        STAGE(buf ^ 1);
        f32x4 stA[4], stB[4];
#pragma unroll
        for (int t = 0; t < 4; t++) {
            f16x8 kf0 = *(const f16x8*)&Ks[buf][kO0 + t * 1024];
            f16x8 kf1 = *(const f16x8*)&Ks[buf][kO1 + t * 1024];
            f32x4 a = {};
            a = __builtin_amdgcn_mfma_f32_16x16x32_f16(kf0, qfA[0], a, 0, 0, 0);
            a = __builtin_amdgcn_mfma_f32_16x16x32_f16(kf1, qfA[1], a, 0, 0, 0);
            stA[t] = a;
            if (withB) {
                f32x4 bb = {};
                bb = __builtin_amdgcn_mfma_f32_16x16x32_f16(kf0, qfB[0], bb, 0, 0, 0);
                bb = __builtin_amdgcn_mfma_f32_16x16x32_f16(kf1, qfB[1], bb, 0, 0, 0);
                stB[t] = bb;
            }
        }
        f16x4 pA[4], pB[4];
#pragma unroll
        for (int t = 0; t < 4; t++) {
            float p0 = EXP2F(stA[t][0]);
            float p1 = EXP2F(stA[t][1]);
            float p2 = EXP2F(stA[t][2]);
            float p3 = EXP2F(stA[t][3]);
            lsA += (p0 + p1) + (p2 + p3);
            f16x2 lo = pkrtz(p0, p1);
            f16x2 hi = pkrtz(p2, p3);
            pA[t][0] = lo[0]; pA[t][1] = lo[1];
            pA[t][2] = hi[0]; pA[t][3] = hi[1];
            if (withB) {
                float b0 = EXP2F(stB[t][0]);
                float b1 = EXP2F(stB[t][1]);
                float b2 = EXP2F(stB[t][2]);
                float b3 = EXP2F(stB[t][3]);
                lsB += (b0 + b1) + (b2 + b3);
                f16x2 blo = pkrtz(b0, b1);
                f16x2 bhi = pkrtz(b2, b3);
                pB[t][0] = blo[0]; pB[t][1] = blo[1];
                pB[t][2] = bhi[0]; pB[t][3] = bhi[1];
            }
        }
#pragma unroll
        for (int t = 0; t < 4; t++) {
#pragma unroll
            for (int dt = 0; dt < 4; dt++) {
                f16x4 vf = *(const f16x4*)&Vs[buf][vO[t] + dt * 1024];
                OA[dt] = __builtin_amdgcn_mfma_f32_16x16x16f16(vf, pA[t], OA[dt], 0, 0, 0);
                if (withB)
                    OB[dt] = __builtin_amdgcn_mfma_f32_16x16x16f16(vf, pB[t], OB[dt], 0, 0, 0);
            }
        }
        __syncthreads();
    };

    // tile t==qb: full for A + causal diagonal for B (t_sub<=w, wave-uniform)
    auto TILE_AdB = [&](int buf) AINL {
        STAGE(buf ^ 1);
        int kv0 = qb * 64;
        f32x4 stA[4];
#pragma unroll
        for (int t = 0; t < 4; t++) {
            f16x8 kf0 = *(const f16x8*)&Ks[buf][kO0 + t * 1024];
            f16x8 kf1 = *(const f16x8*)&Ks[buf][kO1 + t * 1024];
            f32x4 a = {};
            a = __builtin_amdgcn_mfma_f32_16x16x32_f16(kf0, qfA[0], a, 0, 0, 0);
            a = __builtin_amdgcn_mfma_f32_16x16x32_f16(kf1, qfA[1], a, 0, 0, 0);
            stA[t] = a;
            if (t <= w) {
                f32x4 bb = {};
                bb = __builtin_amdgcn_mfma_f32_16x16x32_f16(kf0, qfB[0], bb, 0, 0, 0);
                bb = __builtin_amdgcn_mfma_f32_16x16x32_f16(kf1, qfB[1], bb, 0, 0, 0);
                f16x4 pfd;
#pragma unroll
                for (int rr = 0; rr < 4; rr++) {
                    float sv = bb[rr];
                    if (kv0 + t * 16 + quad * 4 + rr > qidxB) sv = -1e30f;  // causal
                    float pv = EXP2F(sv);
                    lsB += pv;
                    pfd[rr] = (f16_t)pv;
                }
#pragma unroll
                for (int dt = 0; dt < 4; dt++) {
                    f16x4 vf = *(const f16x4*)&Vs[buf][vO[t] + dt * 1024];
                    OB[dt] = __builtin_amdgcn_mfma_f32_16x16x16f16(vf, pfd, OB[dt], 0, 0, 0);
                }
            }
        }
        f16x4 pA[4];
#pragma unroll
        for (int t = 0; t < 4; t++) {
            float p0 = EXP2F(stA[t][0]);
            float p1 = EXP2F(stA[t][1]);
            float p2 = EXP2F(stA[t][2]);
            float p3 = EXP2F(stA[t][3]);
            lsA += (p0 + p1) + (p2 + p3);
            f16x2 lo = pkrtz(p0, p1);
            f16x2 hi = pkrtz(p2, p3);
            pA[t][0] = lo[0]; pA[t][1] = lo[1];
            pA[t][2] = hi[0]; pA[t][3] = hi[1];
        }
#pragma unroll
        for (int t = 0; t < 4; t++) {
#pragma unroll
            for (int dt = 0; dt < 4; dt++) {
                f16x4 vf = *(const f16x4*)&Vs[buf][vO[t] + dt * 1024];
                OA[dt] = __builtin_amdgcn_mfma_f32_16x16x16f16(vf, pA[t], OA[dt], 0, 0, 0);
            }
        }
        __syncthreads();
    };

    // final causal diagonal for A (no staging, no barrier)
    auto DIAG_A = [&](int buf) AINL {
        int kv0 = qa * 64;
#pragma unroll
        for (int t = 0; t < 4; t++) {
            if (t <= w) {
                f16x8 kf0 = *(const f16x8*)&Ks[buf][kO0 + t * 1024];
                f16x8 kf1 = *(const f16x8*)&Ks[buf][kO1 + t * 1024];
                f32x4 a = {};
                a = __builtin_amdgcn_mfma_f32_16x16x32_f16(kf0, qfA[0], a, 0, 0, 0);
                a = __builtin_amdgcn_mfma_f32_16x16x32_f16(kf1, qfA[1], a, 0, 0, 0);
                f16x4 pfd;
#pragma unroll
                for (int rr = 0; rr < 4; rr++) {
                    float sv = a[rr];
                    if (kv0 + t * 16 + quad * 4 + rr > qidxA) sv = -1e30f;  // causal
                    float pv = EXP2F(sv);
                    lsA += pv;
                    pfd[rr] = (f16_t)pv;
                }
#pragma unroll
                for (int dt = 0; dt < 4; dt++) {
                    f16x4 vf = *(const f16x4*)&Vs[buf][vO[t] + dt * 1024];
                    OA[dt] = __builtin_amdgcn_mfma_f32_16x16x16f16(vf, pfd, OA[dt], 0, 0, 0);
                }
            }
        }
    };

    // preload tile 0 into buf 0
    STAGE(0);
    __syncthreads();

    // phase 1: t = 0..qb-1, both qtiles full. buf parity == t&1.
    {
        int t = 0;
        for (; t + 2 <= qb; t += 2) { TILE(0, true); TILE(1, true); }
        if (t < qb) { TILE(0, true); }
    }
    // phase 2: t = qb (A full + B diagonal), buf parity = qb&1
    if (qb & 1) TILE_AdB(1); else TILE_AdB(0);
    // phase 3: t = qb+1 .. qa-1, A only. entry parity = (qb+1)&1
    {
        int t = qb + 1;
        if ((t & 1) && t < qa) { TILE(1, false); t++; }
        for (; t + 2 <= qa; t += 2) { TILE(0, false); TILE(1, false); }
        if (t < qa) { TILE(0, false); }
    }
    // phase 4: A diagonal, buf parity = qa&1
    if (qa & 1) DIAG_A(1); else DIAG_A(0);

    // ---- epilogues: normalize, residual, LN partial stats
    lsA += __shfl_xor(lsA, 16);
    lsA += __shfl_xor(lsA, 32);
    lsB += __shfl_xor(lsB, 16);
    lsB += __shfl_xor(lsB, 32);
    float invA = 1.0f / lsA;
    float invB = 1.0f / lsB;

    float s_acc = 0.0f, ss_acc = 0.0f;

    const float* XpA = X + (bS + qidxA) * Udim + h * Dh;
    bf16_t* RpA = R + (bS + qidxA) * Udim + h * Dh;
#pragma unroll
    for (int dt = 0; dt < 4; dt++) {
        f32x4 xv = *(const f32x4*)(XpA + dt * 16 + quad * 4);
        f32x4 o = OA[dt] * invA + xv;
        bf16x4 ob;
#pragma unroll
        for (int rr = 0; rr < 4; rr++) {
            ob[rr] = (bf16_t)o[rr];
            s_acc += o[rr];
            ss_acc += o[rr] * o[rr];
        }
        *(bf16x4*)(RpA + dt * 16 + quad * 4) = ob;
    }

    const float* XpB = X + (bS + qidxB) * Udim + h * Dh;
    bf16_t* RpB = R + (bS + qidxB) * Udim + h * Dh;
#pragma unroll
    for (int dt = 0; dt < 4; dt++) {
        f32x4 xv = *(const f32x4*)(XpB + dt * 16 + quad * 4);
        f32x4 o = OB[dt] * invB + xv;
        bf16x4 ob;
#pragma unroll
        for (int rr = 0; rr < 4; rr++) {
            ob[rr] = (bf16_t)o[rr];
            s_acc += o[rr];
            ss_acc += o[rr] * o[rr];
        }
        *(bf16x4*)(RpB + dt * 16 + quad * 4) = ob;
    }

#pragma unroll
    for (int o = 1; o < 64; o <<= 1) {
        s_acc += __shfl_xor(s_acc, o);
        ss_acc += __shfl_xor(ss_acc, o);
    }
    __shared__ float red[8];
    if (lane == 0) { red[w] = s_acc; red[4 + w] = ss_acc; }
    __syncthreads();
    if (tid == 0) {
        atomicAdd(&stats[b], red[0] + red[1] + red[2] + red[3]);
        atomicAdd(&stats[2 + b], red[4] + red[5] + red[6] + red[7]);
    }
}

// ---------------------------------------------------------------- LN apply
__global__ __launch_bounds__(256)
void ln_norm(const bf16_t* __restrict__ R, const float* __restrict__ gamma,
             const float* __restrict__ beta, const float* __restrict__ stats,
             float* __restrict__ out)
{
    constexpr float invN = 1.0f / (float)PerBatch;
    float mu[2], inv[2];
#pragma unroll
    for (int b = 0; b < 2; b++) {
        float m = stats[b] * invN;
        float var = stats[2 + b] * invN - m * m;
        mu[b] = m;
        inv[b] = rsqrtf(var + 1e-5f);
    }
    int i = blockIdx.x * 256 + threadIdx.x;      // over 8-elem groups, 512K
    int f = i * 8;
    int b = f >> 21;
    int su = f & (PerBatch - 1);
    bf16x8 rv = *(const bf16x8*)(R + f);
    float4 g0 = *(const float4*)(gamma + su);
    float4 g1 = *(const float4*)(gamma + su + 4);
    float4 be0 = *(const float4*)(beta + su);
    float4 be1 = *(const float4*)(beta + su + 4);
    float4 o0, o1;
    o0.x = ((float)rv[0] - mu[b]) * inv[b] * g0.x + be0.x;
    o0.y = ((float)rv[1] - mu[b]) * inv[b] * g0.y + be0.y;
    o0.z = ((float)rv[2] - mu[b]) * inv[b] * g0.z + be0.z;
    o0.w = ((float)rv[3] - mu[b]) * inv[b] * g0.w + be0.w;
    o1.x = ((float)rv[4] - mu[b]) * inv[b] * g1.x + be1.x;
    o1.y = ((float)rv[5] - mu[b]) * inv[b] * g1.y + be1.y;
    o1.z = ((float)rv[6] - mu[b]) * inv[b] * g1.z + be1.z;
    o1.w = ((float)rv[7] - mu[b]) * inv[b] * g1.w + be1.w;
    *(float4*)(out + f) = o0;
    *(float4*)(out + f + 4) = o1;
}

// ---------------------------------------------------------------- launch
extern "C" void kernel_launch(void* const* d_in, const int* in_sizes, int n_in,
                              void* d_out, int out_size, void* d_ws, size_t ws_size,
                              hipStream_t stream)
{
    const float* X     = (const float*)d_in[0];
    const float* Wq    = (const float*)d_in[1];
    const float* bq    = (const float*)d_in[2];
    const float* Wk    = (const float*)d_in[3];
    const float* bk    = (const float*)d_in[4];
    const float* Wv    = (const float*)d_in[5];
    const float* bv    = (const float*)d_in[6];
    const float* gamma = (const float*)d_in[7];
    const float* beta  = (const float*)d_in[8];
    float* out = (float*)d_out;

    char* ws = (char*)d_ws;
    size_t off = 0;
    auto alloc = [&](size_t bytes) -> void* {
        void* p = ws + off;
        off += (bytes + 255) & ~(size_t)255;
        return p;
    };
    bf16_t* Xb = (bf16_t*)alloc((size_t)Mrows * Cdim * 2);
    bf16_t* Tq = (bf16_t*)alloc((size_t)Cdim * Udim * 2);
    bf16_t* Tk = (bf16_t*)alloc((size_t)Cdim * Udim * 2);
    bf16_t* Tv = (bf16_t*)alloc((size_t)Cdim * Udim * 2);
    f16_t*  Qb = (f16_t*)alloc((size_t)Mrows * Udim * 2);
    f16_t*  Kb = (f16_t*)alloc((size_t)Mrows * Udim * 2);
    f16_t*  Vtb = (f16_t*)alloc((size_t)Mrows * Udim * 2);
    bf16_t* Rb = (bf16_t*)alloc((size_t)Mrows * Udim * 2);
    float*  stats = (float*)alloc(4 * sizeof(float));

    prep<<<dim3(16, 16, 4), 256, 0, stream>>>(X, Wq, Wk, Wv, Xb, Tq, Tk, Tv, stats);
    gemm_qkv<<<dim3(8, 32, 3), 256, 0, stream>>>(Xb, Tq, Tk, Tv, bq, bk, bv, Qb, Kb, Vtb);
    attn9<<<dim3(512), 256, 0, stream>>>(Qb, Kb, Vtb, X, Rb, stats);
    ln_norm<<<dim3(2048), 256, 0, stream>>>(Rb, gamma, beta, stats, out);
}